// Round 1
// baseline (211.636 us; speedup 1.0000x reference)
//
#include <hip/hip_runtime.h>
#include <hip/hip_bf16.h>
#include <math.h>

// Problem: B=8, N=2048, DIN=DOUT=512, adj binary p=0.01
// out = tanh( D^-1/2 (A v I) D^-1/2 (X W) + b )

#define NROWS 16384      // B*N
#define NCOLS 2048       // N
#define DFEAT 512
#define CAP   64         // max edges per row (Binom(2048,0.01): mean 20.5, P(>=64) ~ 0)

// ---------------------------------------------------------------------------
// Pass 1: per-row edge extraction + degree. One wave (64 lanes) per row.
// Deterministic ascending-column edge order via ballot prefix.
// ---------------------------------------------------------------------------
__global__ __launch_bounds__(256) void build_edges(
    const float* __restrict__ adj, int* __restrict__ cnt,
    int* __restrict__ edges, float* __restrict__ dinv) {
  const int wave = threadIdx.x >> 6;
  const int lane = threadIdx.x & 63;
  const int r = blockIdx.x * 4 + wave;          // global row 0..16383
  const int n = r & (NCOLS - 1);                // row index within batch
  const float* row = adj + (size_t)r * NCOLS;
  int base = 0;
  #pragma unroll 4
  for (int k = 0; k < NCOLS / 64; ++k) {
    const int col = k * 64 + lane;
    const float v = row[col];
    const bool flag = (v != 0.0f) || (col == n);   // force self-loop
    const unsigned long long mask = __ballot(flag);
    if (flag) {
      const int pos = base + __popcll(mask & ((1ull << lane) - 1ull));
      if (pos < CAP) edges[(size_t)r * CAP + pos] = col;
    }
    base += __popcll(mask);
  }
  if (lane == 0) {
    cnt[r] = base < CAP ? base : CAP;
    dinv[r] = rsqrtf((float)base);                 // deg >= 1 always
  }
}

// ---------------------------------------------------------------------------
// Pass 2: h = X @ W   (fp32, LDS-tiled, 64x64 tile, BK=16, 4x4 per thread)
// X: [16384,512] row-major, W: [512,512] row-major, H: [16384,512]
// ---------------------------------------------------------------------------
#define BM 64
#define BN 64
#define BK 16
#define LDP 72   // padded leading dim (multiple of 4 for float4 alignment)

__global__ __launch_bounds__(256) void gemm_xw(
    const float* __restrict__ X, const float* __restrict__ W,
    float* __restrict__ H) {
  __shared__ float As[BK][LDP];   // transposed: As[k][m]
  __shared__ float Bs[BK][LDP];   // Bs[k][n]
  const int tid = threadIdx.x;
  const int tx = tid & 15;        // N direction
  const int ty = tid >> 4;        // M direction
  const int bm = blockIdx.x * BM;
  const int bn = blockIdx.y * BN;

  float acc[4][4];
  #pragma unroll
  for (int i = 0; i < 4; ++i)
    #pragma unroll
    for (int j = 0; j < 4; ++j) acc[i][j] = 0.0f;

  for (int k0 = 0; k0 < DFEAT; k0 += BK) {
    // A tile: 64 rows x 16 cols
    #pragma unroll
    for (int i = 0; i < 4; ++i) {
      const int idx = tid + 256 * i;
      const int m = idx >> 4, kk = idx & 15;
      As[kk][m] = X[(size_t)(bm + m) * DFEAT + k0 + kk];
    }
    // B tile: 16 rows x 64 cols
    #pragma unroll
    for (int i = 0; i < 4; ++i) {
      const int idx = tid + 256 * i;
      const int kk = idx >> 6, nn = idx & 63;
      Bs[kk][nn] = W[(size_t)(k0 + kk) * DFEAT + bn + nn];
    }
    __syncthreads();
    #pragma unroll
    for (int kk = 0; kk < BK; ++kk) {
      const float4 a = *(const float4*)&As[kk][ty * 4];
      const float4 bv = *(const float4*)&Bs[kk][tx * 4];
      acc[0][0] += a.x * bv.x; acc[0][1] += a.x * bv.y; acc[0][2] += a.x * bv.z; acc[0][3] += a.x * bv.w;
      acc[1][0] += a.y * bv.x; acc[1][1] += a.y * bv.y; acc[1][2] += a.y * bv.z; acc[1][3] += a.y * bv.w;
      acc[2][0] += a.z * bv.x; acc[2][1] += a.z * bv.y; acc[2][2] += a.z * bv.z; acc[2][3] += a.z * bv.w;
      acc[3][0] += a.w * bv.x; acc[3][1] += a.w * bv.y; acc[3][2] += a.w * bv.z; acc[3][3] += a.w * bv.w;
    }
    __syncthreads();
  }
  #pragma unroll
  for (int i = 0; i < 4; ++i) {
    float4 v;
    v.x = acc[i][0]; v.y = acc[i][1]; v.z = acc[i][2]; v.w = acc[i][3];
    *(float4*)&H[(size_t)(bm + ty * 4 + i) * DFEAT + bn + tx * 4] = v;
  }
}

// ---------------------------------------------------------------------------
// Pass 3: agg[r,:] = dinv[r] * sum_{m in nbr(r)} dinv[m] * h[b,m,:]
//         out = tanh(agg + bias)
// One block (256 threads) per row; thread t owns output elems 2t, 2t+1.
// XCD swizzle: block j -> XCD j%8 handles batch j%8 (its 4MB h slice fits L2).
// ---------------------------------------------------------------------------
__global__ __launch_bounds__(256) void aggregate(
    const float* __restrict__ h, const int* __restrict__ cnt,
    const int* __restrict__ edges, const float* __restrict__ dinv,
    const float* __restrict__ bias, float* __restrict__ out) {
  __shared__ int   eL[CAP];
  __shared__ float wL[CAP];
  const int j = blockIdx.x;
  const int r = (j & 7) * NCOLS + (j >> 3);   // bijective: batch = j%8 -> XCD j%8
  const int b = r >> 11;
  const int tid = threadIdx.x;
  const int c = cnt[r];
  if (tid < c) {
    const int m = edges[(size_t)r * CAP + tid];
    eL[tid] = m;
    wL[tid] = dinv[(b << 11) + m];
  }
  __syncthreads();

  float2 acc = make_float2(0.0f, 0.0f);
  for (int e = 0; e < c; ++e) {
    const int m = eL[e];
    const float w = wL[e];
    const float2 hv = *(const float2*)&h[((size_t)(b << 11) + m) * DFEAT + tid * 2];
    acc.x += w * hv.x;
    acc.y += w * hv.y;
  }
  const float dn = dinv[r];
  const float2 bv = *(const float2*)&bias[tid * 2];
  float2 o;
  o.x = tanhf(acc.x * dn + bv.x);
  o.y = tanhf(acc.y * dn + bv.y);
  *(float2*)&out[(size_t)r * DFEAT + tid * 2] = o;
}

// ---------------------------------------------------------------------------
extern "C" void kernel_launch(void* const* d_in, const int* in_sizes, int n_in,
                              void* d_out, int out_size, void* d_ws, size_t ws_size,
                              hipStream_t stream) {
  const float* X    = (const float*)d_in[0];   // [8,2048,512]
  const float* adj  = (const float*)d_in[1];   // [8,2048,2048]
  const float* W    = (const float*)d_in[2];   // [512,512]
  const float* bias = (const float*)d_in[3];   // [512]
  float* out = (float*)d_out;

  char* ws = (char*)d_ws;
  float* h    = (float*)ws;                                    // 33,554,432 B
  float* dinv = (float*)(ws + 33554432);                       //     65,536 B
  int*   cnt  = (int*)  (ws + 33554432 + 65536);               //     65,536 B
  int*   edges= (int*)  (ws + 33554432 + 131072);              //  4,194,304 B
  // total ws needed: ~36.2 MB

  build_edges<<<NROWS / 4, 256, 0, stream>>>(adj, cnt, edges, dinv);
  gemm_xw<<<dim3(NROWS / BM, DFEAT / BN), 256, 0, stream>>>(X, W, h);
  aggregate<<<NROWS, 256, 0, stream>>>(h, cnt, edges, dinv, bias, out);
}

// Round 2
// 82.588 us; speedup vs baseline: 2.5626x; 2.5626x over previous
//
#include <hip/hip_runtime.h>
#include <hip/hip_bf16.h>
#include <math.h>

// Problem: B=8, N=2048, DIN=DOUT=512, adj binary p=0.01
// out = tanh( D^-1/2 (A v I) D^-1/2 (X W) + b )

#define NROWS 16384      // B*N
#define NCOLS 2048       // N
#define DF    512
#define CAP   64         // max edges/row (Binom(2048,0.01): mean 21.5, P(>=64) ~ 0)

typedef __attribute__((ext_vector_type(8))) short bf16x8;   // 8 bf16 (4 VGPRs)
typedef __attribute__((ext_vector_type(4))) float f32x4;

typedef const void __attribute__((address_space(1))) gvoid_t;
typedef void __attribute__((address_space(3))) svoid_t;

// ---------------------------------------------------------------------------
// Pass 0: convert X -> bf16 (blocks 0..8191) ; W -> W^T bf16 (blocks 8192..8255)
// ---------------------------------------------------------------------------
__global__ __launch_bounds__(256) void convert_kernel(
    const float* __restrict__ X, const float* __restrict__ W,
    __hip_bfloat16* __restrict__ Xb, __hip_bfloat16* __restrict__ WT) {
  __shared__ float t[64][65];
  const int bid = blockIdx.x;
  const int tid = threadIdx.x;
  if (bid < 8192) {
    const int idx = bid * 256 + tid;               // float4 index; 8192*256*4 = 8,388,608 floats
    const float4 v = ((const float4*)X)[idx];
    union { ushort4 u; __hip_bfloat16 h[4]; } p;
    p.h[0] = __float2bfloat16(v.x);
    p.h[1] = __float2bfloat16(v.y);
    p.h[2] = __float2bfloat16(v.z);
    p.h[3] = __float2bfloat16(v.w);
    ((ushort4*)Xb)[idx] = p.u;
  } else {
    const int b2 = bid - 8192;                     // 0..63  (8x8 tiles of 64x64)
    const int bx = b2 & 7, by = b2 >> 3;
    const int tx = tid & 63, ty = tid >> 6;        // 4 rows per pass
    #pragma unroll
    for (int i = 0; i < 16; ++i)
      t[ty + i * 4][tx] = W[(size_t)(by * 64 + ty + i * 4) * DF + bx * 64 + tx];
    __syncthreads();
    #pragma unroll
    for (int i = 0; i < 16; ++i)                   // WT[n][k] = W[k][n]
      WT[(size_t)(bx * 64 + ty + i * 4) * DF + by * 64 + tx] =
          __float2bfloat16(t[tx][ty + i * 4]);
  }
}

// ---------------------------------------------------------------------------
// Pass 1: edge extraction + degrees. One wave per row, float4 loads.
// Deterministic compaction (j-major within each 256-col chunk).
// ---------------------------------------------------------------------------
__global__ __launch_bounds__(256) void build_edges(
    const float* __restrict__ adj, int* __restrict__ cnt,
    int* __restrict__ edges, float* __restrict__ dinv) {
  const int wave = threadIdx.x >> 6;
  const int lane = threadIdx.x & 63;
  const int r = blockIdx.x * 4 + wave;
  const int n = r & (NCOLS - 1);
  const float4* row4 = (const float4*)(adj + (size_t)r * NCOLS);
  const unsigned long long lt = (1ull << lane) - 1ull;
  int base = 0;
  for (int k = 0; k < NCOLS / 256; ++k) {          // 8 iterations
    const float4 v = row4[k * 64 + lane];
    const int c0 = k * 256 + lane * 4;
    const bool f0 = (v.x != 0.0f) || (c0 + 0 == n);
    const bool f1 = (v.y != 0.0f) || (c0 + 1 == n);
    const bool f2 = (v.z != 0.0f) || (c0 + 2 == n);
    const bool f3 = (v.w != 0.0f) || (c0 + 3 == n);
    const unsigned long long m0 = __ballot(f0);
    const unsigned long long m1 = __ballot(f1);
    const unsigned long long m2 = __ballot(f2);
    const unsigned long long m3 = __ballot(f3);
    const int n0 = __popcll(m0), n1 = __popcll(m1), n2 = __popcll(m2), n3 = __popcll(m3);
    if (f0) { int p = base + __popcll(m0 & lt);                 if (p < CAP) edges[(size_t)r * CAP + p] = c0 + 0; }
    if (f1) { int p = base + n0 + __popcll(m1 & lt);            if (p < CAP) edges[(size_t)r * CAP + p] = c0 + 1; }
    if (f2) { int p = base + n0 + n1 + __popcll(m2 & lt);       if (p < CAP) edges[(size_t)r * CAP + p] = c0 + 2; }
    if (f3) { int p = base + n0 + n1 + n2 + __popcll(m3 & lt);  if (p < CAP) edges[(size_t)r * CAP + p] = c0 + 3; }
    base += n0 + n1 + n2 + n3;
  }
  if (lane == 0) {
    cnt[r] = base < CAP ? base : CAP;
    dinv[r] = rsqrtf((float)base);                 // deg >= 1 (forced self-loop)
  }
}

// ---------------------------------------------------------------------------
// Pass 2: H = Xb @ WT^T  (bf16 MFMA, 128x128 tile, BK=32, 4 waves 2x2)
// Xb: [16384,512] bf16 row-major; WT: [512,512] bf16 (WT[n][k]); H: bf16
// m97 structure: global_load_lds width-16 staging, 2 barriers per K-step.
// ---------------------------------------------------------------------------
__global__ __launch_bounds__(256) void gemm_bf16(
    const __hip_bfloat16* __restrict__ A, const __hip_bfloat16* __restrict__ BT,
    __hip_bfloat16* __restrict__ H) {
  __shared__ __hip_bfloat16 As[128 * 32];          // 8 KB, linear [row][k]
  __shared__ __hip_bfloat16 Bs[128 * 32];          // 8 KB, linear [n][k]
  const int tid = threadIdx.x;
  const int lane = tid & 63;
  const int w = tid >> 6;
  const int bm = blockIdx.y * 128;                 // grid (4,128): A-panel-sharing blocks adjacent
  const int bn = blockIdx.x * 128;
  const int wm = (w >> 1) * 64;
  const int wn = (w & 1) * 64;

  f32x4 acc[4][4] = {};

  const int srow = tid >> 2;                       // 0..63: row within 64-row staging chunk
  const int scol = (tid & 3) * 8;                  // element col within BK=32
  const int kl = (lane >> 4) * 8;                  // fragment k sub-chunk
  const int rl = lane & 15;                        // fragment row/col index

  for (int k0 = 0; k0 < DF; k0 += 32) {
    #pragma unroll
    for (int i = 0; i < 2; ++i) {
      const __hip_bfloat16* ga = A + (size_t)(bm + i * 64 + srow) * DF + k0 + scol;
      const __hip_bfloat16* gb = BT + (size_t)(bn + i * 64 + srow) * DF + k0 + scol;
      char* la = (char*)As + i * 4096 + w * 1024;  // HW adds lane*16
      char* lb = (char*)Bs + i * 4096 + w * 1024;
      __builtin_amdgcn_global_load_lds((gvoid_t*)ga, (svoid_t*)la, 16, 0, 0);
      __builtin_amdgcn_global_load_lds((gvoid_t*)gb, (svoid_t*)lb, 16, 0, 0);
    }
    __syncthreads();                               // vmcnt(0) drain + barrier

    bf16x8 af[4], bf[4];
    #pragma unroll
    for (int mi = 0; mi < 4; ++mi)
      af[mi] = *(const bf16x8*)&As[(wm + mi * 16 + rl) * 32 + kl];
    #pragma unroll
    for (int ni = 0; ni < 4; ++ni)
      bf[ni] = *(const bf16x8*)&Bs[(wn + ni * 16 + rl) * 32 + kl];
    #pragma unroll
    for (int mi = 0; mi < 4; ++mi)
      #pragma unroll
      for (int ni = 0; ni < 4; ++ni)
        acc[mi][ni] = __builtin_amdgcn_mfma_f32_16x16x32_bf16(af[mi], bf[ni], acc[mi][ni], 0, 0, 0);
    __syncthreads();                               // before next-iter LDS overwrite
  }

  // epilogue: D col=lane&15, row=(lane>>4)*4+j
  const int rq = (lane >> 4) * 4;
  #pragma unroll
  for (int mi = 0; mi < 4; ++mi)
    #pragma unroll
    for (int ni = 0; ni < 4; ++ni) {
      const int col = bn + wn + ni * 16 + rl;
      #pragma unroll
      for (int j = 0; j < 4; ++j) {
        const int row = bm + wm + mi * 16 + rq + j;
        H[(size_t)row * DF + col] = __float2bfloat16(acc[mi][ni][j]);
      }
    }
}

// ---------------------------------------------------------------------------
// Pass 3: out[r,:] = tanh( dinv[r] * sum_m dinv[m] * h[b,m,:] + bias )
// One block per row; batch->XCD swizzle keeps each 2MB bf16 h-slice L2-hot.
// ---------------------------------------------------------------------------
__global__ __launch_bounds__(256) void aggregate(
    const __hip_bfloat16* __restrict__ h, const int* __restrict__ cnt,
    const int* __restrict__ edges, const float* __restrict__ dinv,
    const float* __restrict__ bias, float* __restrict__ out) {
  __shared__ int   eL[CAP];
  __shared__ float wL[CAP];
  const int j = blockIdx.x;
  const int r = (j & 7) * NCOLS + (j >> 3);        // bijective: batch = j%8 -> XCD j%8
  const int b = r >> 11;
  const int tid = threadIdx.x;
  const int c = cnt[r];
  if (tid < c) {
    const int m = edges[(size_t)r * CAP + tid];
    eL[tid] = m;
    wL[tid] = dinv[(b << 11) + m];
  }
  __syncthreads();

  float ax = 0.0f, ay = 0.0f;
  for (int e = 0; e < c; ++e) {
    const int m = eL[e];
    const float wgt = wL[e];
    const unsigned hv = *(const unsigned*)&h[((size_t)(b << 11) + m) * DF + tid * 2];
    ax += wgt * __uint_as_float(hv << 16);          // low bf16
    ay += wgt * __uint_as_float(hv & 0xffff0000u);  // high bf16
  }
  const float dn = dinv[r];
  const float2 bv = *(const float2*)&bias[tid * 2];
  float2 o;
  o.x = tanhf(ax * dn + bv.x);
  o.y = tanhf(ay * dn + bv.y);
  *(float2*)&out[(size_t)r * DF + tid * 2] = o;
}

// ---------------------------------------------------------------------------
extern "C" void kernel_launch(void* const* d_in, const int* in_sizes, int n_in,
                              void* d_out, int out_size, void* d_ws, size_t ws_size,
                              hipStream_t stream) {
  const float* X    = (const float*)d_in[0];   // [8,2048,512]
  const float* adj  = (const float*)d_in[1];   // [8,2048,2048]
  const float* W    = (const float*)d_in[2];   // [512,512]
  const float* bias = (const float*)d_in[3];   // [512]
  float* out = (float*)d_out;

  char* ws = (char*)d_ws;
  __hip_bfloat16* Xb   = (__hip_bfloat16*)(ws);                    // 16,777,216 B
  __hip_bfloat16* WT   = (__hip_bfloat16*)(ws + 16777216);         //    524,288 B
  __hip_bfloat16* h    = (__hip_bfloat16*)(ws + 17301504);         // 16,777,216 B
  float*          dinv = (float*)(ws + 34078720);                  //     65,536 B
  int*            cnt  = (int*)  (ws + 34144256);                  //     65,536 B
  int*            edges= (int*)  (ws + 34209792);                  //  4,194,304 B
  // total ws: 38,404,096 B

  convert_kernel<<<8256, 256, 0, stream>>>(X, W, Xb, WT);
  build_edges<<<NROWS / 4, 256, 0, stream>>>(adj, cnt, edges, dinv);
  gemm_bf16<<<dim3(4, 128), 256, 0, stream>>>(Xb, WT, h);
  aggregate<<<NROWS, 256, 0, stream>>>(h, cnt, edges, dinv, bias, out);
}